// Round 1
// 833.209 us; speedup vs baseline: 1.2230x; 1.2230x over previous
//
#include <hip/hip_runtime.h>
#include <hip/hip_bf16.h>

// Problem constants
#define T_TOK 8192
#define E_EXP 8
#define D_HID 1024
#define F_FFN 4096
#define C_CAP 2048   // T * 2.0 / E

typedef __attribute__((ext_vector_type(8))) short bf16x8;  // 8 bf16 (4 VGPRs)
typedef __attribute__((ext_vector_type(4))) float f32x4;   // 4 fp32 acc

// Async global->LDS, 16 B per lane. LDS dest is wave-uniform base + lane*16;
// source address may be per-lane (gather OK).
__device__ __forceinline__ void load_lds16(const void* g, void* l) {
    __builtin_amdgcn_global_load_lds(
        (const __attribute__((address_space(1))) unsigned int*)g,
        (__attribute__((address_space(3))) unsigned int*)l, 16, 0, 0);
}

// gelu(v) = v * sigmoid(1.595769 v + 0.0713548 v^3); __expf -> v_exp_f32.
__device__ __forceinline__ float gelu_fast(float v) {
    float z = v * (1.5957691216057308f + 0.07135481627f * v * v);
    return v / (1.0f + __expf(-z));
}

// ---------------------------------------------------------------------------
// Kernel 1: router gating (fp32 exact). One wave per token.
// ---------------------------------------------------------------------------
__global__ __launch_bounds__(256) void gating_kernel(
    const float* __restrict__ x, const float* __restrict__ Wg,
    float* __restrict__ gatesT)
{
    const int token = blockIdx.x * 4 + (threadIdx.x >> 6);
    const int lane  = threadIdx.x & 63;
    const float* xr = x + (size_t)token * D_HID;

    float acc[E_EXP];
#pragma unroll
    for (int e = 0; e < E_EXP; ++e) acc[e] = 0.0f;

    for (int c = 0; c < D_HID; c += 64) {
        float xv = xr[c + lane];
        const float* wr = Wg + (size_t)(c + lane) * E_EXP;
#pragma unroll
        for (int e = 0; e < E_EXP; ++e) acc[e] += xv * wr[e];
    }
#pragma unroll
    for (int e = 0; e < E_EXP; ++e) {
        for (int off = 32; off; off >>= 1) acc[e] += __shfl_down(acc[e], off);
    }
    if (lane == 0) {
        float m = acc[0];
#pragma unroll
        for (int e = 1; e < E_EXP; ++e) m = fmaxf(m, acc[e]);
        float ex[E_EXP];
        float s = 0.0f;
#pragma unroll
        for (int e = 0; e < E_EXP; ++e) { ex[e] = expf(acc[e] - m); s += ex[e]; }
        float inv = 1.0f / s;
#pragma unroll
        for (int e = 0; e < E_EXP; ++e) gatesT[(size_t)e * T_TOK + token] = ex[e] * inv;
    }
}

// ---------------------------------------------------------------------------
// Kernel 2: aux loss = E * (C/T) * mean(gates)  (frac_routed == C/T exactly)
// ---------------------------------------------------------------------------
__global__ __launch_bounds__(256) void aux_kernel(
    const float* __restrict__ gatesT, float* __restrict__ aux_out)
{
    float s = 0.0f;
    for (int i = threadIdx.x; i < T_TOK * E_EXP; i += 256) s += gatesT[i];
    for (int off = 32; off; off >>= 1) s += __shfl_down(s, off);
    __shared__ float red[4];
    if ((threadIdx.x & 63) == 0) red[threadIdx.x >> 6] = s;
    __syncthreads();
    if (threadIdx.x == 0) {
        float tot = red[0] + red[1] + red[2] + red[3];
        float frac = (float)C_CAP / (float)T_TOK;
        aux_out[0] = (float)E_EXP * frac * (tot / (float)T_TOK);
    }
}

// ---------------------------------------------------------------------------
// Kernel 3: exact per-expert top-C bitonic sort (64-bit keys, jax tie-break).
// Also builds the token -> (expert, slot) inverse map for the combine pass.
// ---------------------------------------------------------------------------
__global__ __launch_bounds__(1024) void topk_kernel(
    const float* __restrict__ gatesT, int* __restrict__ topidx,
    float* __restrict__ topval, int* __restrict__ cnt, int* __restrict__ inv)
{
    __shared__ unsigned long long keys[T_TOK];
    const int e = blockIdx.x;
    const float* row = gatesT + (size_t)e * T_TOK;

    for (int i = threadIdx.x; i < T_TOK; i += blockDim.x) {
        unsigned int b = __float_as_uint(row[i]);
        b = (b & 0x80000000u) ? ~b : (b | 0x80000000u);
        keys[i] = ((unsigned long long)b << 32) | (unsigned int)(T_TOK - 1 - i);
    }
    __syncthreads();

    for (int k = 2; k <= T_TOK; k <<= 1) {
        for (int j = k >> 1; j > 0; j >>= 1) {
            for (int i = threadIdx.x; i < T_TOK; i += blockDim.x) {
                int p = i ^ j;
                if (p > i) {
                    bool desc = ((i & k) == 0);
                    unsigned long long a = keys[i];
                    unsigned long long b = keys[p];
                    bool sw = desc ? (a < b) : (a > b);
                    if (sw) { keys[i] = b; keys[p] = a; }
                }
            }
            __syncthreads();
        }
    }

    for (int c = threadIdx.x; c < C_CAP; c += blockDim.x) {
        unsigned long long kk = keys[c];
        int idx = T_TOK - 1 - (int)(kk & 0xFFFFFFFFu);
        unsigned int b = (unsigned int)(kk >> 32);
        b = (b & 0x80000000u) ? (b & 0x7FFFFFFFu) : ~b;
        topidx[e * C_CAP + c] = idx;
        topval[e * C_CAP + c] = __uint_as_float(b);
        int slot = atomicAdd(&cnt[idx], 1);   // <=8 entries per token (1/expert)
        inv[idx * E_EXP + slot] = e * C_CAP + c;
    }
}

// ---------------------------------------------------------------------------
// Kernel 4: fp32 -> bf16 elementwise (x), vectorized.
// ---------------------------------------------------------------------------
__global__ __launch_bounds__(256) void cvt_bf16_kernel(
    const float* __restrict__ in, __hip_bfloat16* __restrict__ out, int n4)
{
    int i = blockIdx.x * 256 + threadIdx.x;
    if (i >= n4) return;
    float4 v = ((const float4*)in)[i];
    union { __hip_bfloat16 h[4]; short4 s; } u;
    u.h[0] = __float2bfloat16(v.x); u.h[1] = __float2bfloat16(v.y);
    u.h[2] = __float2bfloat16(v.z); u.h[3] = __float2bfloat16(v.w);
    ((short4*)out)[i] = u.s;
}

// ---------------------------------------------------------------------------
// Kernel 5: per-expert transpose+convert: [E][R][Cn] fp32 -> [E][Cn][R] bf16.
// ---------------------------------------------------------------------------
__global__ __launch_bounds__(256) void transpose_bf16_kernel(
    const float* __restrict__ in, __hip_bfloat16* __restrict__ out,
    int R, int Cn)
{
    __shared__ float tile[64][65];
    const int e = blockIdx.z;
    in  += (size_t)e * R * Cn;
    out += (size_t)e * R * Cn;
    const int c0 = blockIdx.x * 64, r0 = blockIdx.y * 64;
    const int tid = threadIdx.x;

    const int lr = tid >> 4, lc4 = (tid & 15) * 4;
#pragma unroll
    for (int it = 0; it < 4; ++it) {
        int r = lr + it * 16;
        float4 v = *(const float4*)(in + (size_t)(r0 + r) * Cn + c0 + lc4);
        tile[r][lc4 + 0] = v.x; tile[r][lc4 + 1] = v.y;
        tile[r][lc4 + 2] = v.z; tile[r][lc4 + 3] = v.w;
    }
    __syncthreads();

    const int ocb = tid >> 3, j0 = (tid & 7) * 8;
#pragma unroll
    for (int it = 0; it < 2; ++it) {
        int oc = ocb + it * 32;
        union { __hip_bfloat16 h[8]; uint4 v; } u;
#pragma unroll
        for (int j = 0; j < 8; ++j) u.h[j] = __float2bfloat16(tile[j0 + j][oc]);
        *(uint4*)(out + (size_t)(c0 + oc) * R + r0 + j0) = u.v;
    }
}

// ===========================================================================
// 256x256 8-phase GEMM template (plain-HIP port of the verified m201/HK
// schedule): BK=64, 8 waves (2M x 4N), 512 threads, 128 KiB LDS dbuf,
// XOR-swizzled LDS (chunk ^= row&7, involution; linear global_load_lds dest
// with inverse-swizzled per-lane SOURCE), counted vmcnt(4) once per K-tile,
// setprio(1) around each 16-MFMA cluster.
//
// Stage schedule per K-tile u (one half-tile = 128 rows x 64 K of one
// operand = 2 global_load_lds per thread):
//   ph0: stage Alo(u+1)   ph1: stage Ahi(u+1)
//   ph2: stage Blo(u+2)   ph3: stage Bhi(u+2), then vmcnt(4), barrier
// Derivation invariants (checked, do not perturb):
//  - reads of tile u touch only its own wave's A-half / B-half, all 4 halves
//    of u are drained by ph3(u-1)'s vmcnt(4) (Ahi(u) is 3rd-from-last issue).
//  - every stage into buffer buf[x] is issued >=1 full barrier after the last
//    LDS read of the previous tenant (A halves last read ph2, B halves ph1).
// ===========================================================================

#define BARS do { __builtin_amdgcn_s_barrier(); __builtin_amdgcn_sched_barrier(0); } while (0)
#define WLG  do { asm volatile("s_waitcnt lgkmcnt(0)" ::: "memory"); __builtin_amdgcn_sched_barrier(0); } while (0)
#define VMC4 asm volatile("s_waitcnt vmcnt(4)" ::: "memory")
#define VMC0 asm volatile("s_waitcnt vmcnt(0)" ::: "memory")

// staging: half hh (0=rows 0-127, 1=rows 128-255) of tile s
#define G_STAGE_A(hh, s) do { int b_ = (((s) & 1) << 15) + ((hh) << 14) + (w << 10); \
    load_lds16(Abase + (size_t)(aog[hh][0] + (s) * 128), smem + b_); \
    load_lds16(Abase + (size_t)(aog[hh][1] + (s) * 128), smem + b_ + 8192); } while (0)
#define G_STAGE_B(hh, s) do { int b_ = 65536 + (((s) & 1) << 15) + ((hh) << 14) + (w << 10); \
    load_lds16(Bbase + (size_t)(bog[hh][0] + (s) * 128), smem + b_); \
    load_lds16(Bbase + (size_t)(bog[hh][1] + (s) * 128), smem + b_ + 8192); } while (0)

// register-subtile reads (swizzled): row&7 == lane&7 for every fragment row
#define READ_A(mh) do { _Pragma("unroll") for (int mi = 0; mi < 4; ++mi) { \
    aF[mi][0] = *(const bf16x8*)(Ab + (arow + (mh) * 8192 + mi * 2048 + kc0)); \
    aF[mi][1] = *(const bf16x8*)(Ab + (arow + (mh) * 8192 + mi * 2048 + kc1)); } } while (0)
#define READ_B(nh, dst) do { _Pragma("unroll") for (int ni = 0; ni < 2; ++ni) { \
    dst[ni][0] = *(const bf16x8*)(Bb + (brow + (nh) * 4096 + ni * 2048 + kc0)); \
    dst[ni][1] = *(const bf16x8*)(Bb + (brow + (nh) * 4096 + ni * 2048 + kc1)); } } while (0)

#define QUAD(mh, nh, BF) do { \
    __builtin_amdgcn_s_setprio(1); \
    _Pragma("unroll") for (int mi = 0; mi < 4; ++mi) \
    _Pragma("unroll") for (int ni = 0; ni < 2; ++ni) { \
        acc[(mh)*4+mi][(nh)*2+ni] = __builtin_amdgcn_mfma_f32_16x16x32_bf16( \
            aF[mi][0], BF[ni][0], acc[(mh)*4+mi][(nh)*2+ni], 0, 0, 0); \
        acc[(mh)*4+mi][(nh)*2+ni] = __builtin_amdgcn_mfma_f32_16x16x32_bf16( \
            aF[mi][1], BF[ni][1], acc[(mh)*4+mi][(nh)*2+ni], 0, 0, 0); } \
    __builtin_amdgcn_s_setprio(0); } while (0)

#define GEMM_PROLOGUE() do { \
    G_STAGE_A(0, 0); G_STAGE_A(1, 0); G_STAGE_B(0, 0); G_STAGE_B(1, 0); \
    G_STAGE_B(0, 1); G_STAGE_B(1, 1); \
    VMC4; BARS; } while (0)

#define GEMM_TILE(t, NT) do { \
    const char* Ab = smem + (((t) & 1) << 15); \
    const char* Bb = smem + 65536 + (((t) & 1) << 15); \
    /* phase 0 */ \
    READ_A(0); READ_B(0, bF0); \
    if ((t) + 1 < (NT)) G_STAGE_A(0, (t) + 1); \
    BARS; WLG; QUAD(0, 0, bF0); BARS; \
    /* phase 1 */ \
    READ_B(1, bF1); \
    if ((t) + 1 < (NT)) G_STAGE_A(1, (t) + 1); \
    BARS; WLG; QUAD(0, 1, bF1); BARS; \
    /* phase 2 */ \
    READ_A(1); \
    if ((t) + 2 < (NT)) G_STAGE_B(0, (t) + 2); \
    BARS; WLG; QUAD(1, 1, bF1); BARS; \
    /* phase 3 */ \
    if ((t) + 2 < (NT)) G_STAGE_B(1, (t) + 2); \
    BARS; WLG; QUAD(1, 0, bF0); \
    if ((t) + 2 < (NT)) { VMC4; } else { VMC0; } \
    BARS; } while (0)

// ---------------------------------------------------------------------------
// Kernel 6: GEMM1 (all experts): h[e] = gelu(gather(x)[C,D] @ W1t[e]^T + b1[e])
// M=C=2048, N=F=4096, K=D=1024. Grid 1024 blocks x 512 thr, XCD-swizzled.
// ---------------------------------------------------------------------------
__global__ __launch_bounds__(512, 2) void gemm1_kernel(
    const __hip_bfloat16* __restrict__ xb,   // [T][D]
    const __hip_bfloat16* __restrict__ W1t,  // [E][F][D]
    const float* __restrict__ b1,            // [E][F]
    const int* __restrict__ topidx,          // [E][C]
    __hip_bfloat16* __restrict__ hbuf)       // [E][C][F]
{
    __shared__ __align__(16) char smem[131072];   // [A0|A1|B0|B1] x 32 KiB
    const int tid = threadIdx.x;
    const int w = tid >> 6, lane = tid & 63;
    const int wr = w >> 2, wc = w & 3;
    const int fr = lane & 15, qlane = lane >> 4;

    // XCD-bijective swizzle (1024 % 8 == 0), x fastest
    const int bid = blockIdx.x;
    const int wg  = (bid & 7) * 128 + (bid >> 3);
    const int n0  = (wg & 15) * 256;
    const int m0  = ((wg >> 4) & 7) * 256;
    const int e   = wg >> 7;

    const char* Abase = (const char*)xb;
    const char* Bbase = (const char*)(W1t + (size_t)e * F_FFN * D_HID);

    // staging source byte offsets (inverse-swizzled column chunk)
    const int cc = (tid & 7) ^ ((tid >> 3) & 7);
    int aog[2][2], bog[2][2];
#pragma unroll
    for (int hh = 0; hh < 2; ++hh)
#pragma unroll
        for (int j = 0; j < 2; ++j) {
            int r   = m0 + hh * 128 + j * 64 + (tid >> 3);
            int tok = topidx[e * C_CAP + r];
            aog[hh][j] = (tok * D_HID + cc * 8) * 2;
            int n = n0 + hh * 128 + j * 64 + (tid >> 3);
            bog[hh][j] = (n * D_HID + cc * 8) * 2;
        }

    const int arow = (wr * 128 + fr) * 128;
    const int brow = (wc * 64 + fr) * 128;
    const int kc0  = ((qlane)     ^ (lane & 7)) * 16;
    const int kc1  = ((4 + qlane) ^ (lane & 7)) * 16;

    bf16x8 aF[4][2], bF0[2][2], bF1[2][2];
    f32x4 acc[8][4];
#pragma unroll
    for (int mi = 0; mi < 8; ++mi)
#pragma unroll
        for (int ni = 0; ni < 4; ++ni) acc[mi][ni] = (f32x4){0.f, 0.f, 0.f, 0.f};

    GEMM_PROLOGUE();
    for (int t = 0; t < 16; ++t) GEMM_TILE(t, 16);   // NT = 1024/64

    // Epilogue: bias + gelu -> bf16. Quarter-wave covers a full 128 B line
    // across the 4 ni stores (cols wc*64 + {0,16,32,48} + fr).
    const int q4 = qlane * 4;
    float b1v[4];
#pragma unroll
    for (int ni = 0; ni < 4; ++ni)
        b1v[ni] = b1[e * F_FFN + n0 + wc * 64 + ni * 16 + fr];
#pragma unroll
    for (int mi = 0; mi < 8; ++mi)
#pragma unroll
        for (int r = 0; r < 4; ++r) {
            size_t row = (size_t)e * C_CAP + m0 + wr * 128 + mi * 16 + q4 + r;
            __hip_bfloat16* orow = hbuf + row * F_FFN + n0 + wc * 64;
#pragma unroll
            for (int ni = 0; ni < 4; ++ni)
                orow[ni * 16 + fr] =
                    __float2bfloat16(gelu_fast(acc[mi][ni][r] + b1v[ni]));
        }
}

// ---------------------------------------------------------------------------
// Kernel 7: GEMM2 (all experts): yo[e][c] = (h[e] @ W2t[e]^T + b2[e]) * gate
// M=C=2048, N=D=1024, K=F=4096. Grid 256 blocks x 512 thr (1/CU).
// ---------------------------------------------------------------------------
__global__ __launch_bounds__(512, 2) void gemm2_kernel(
    const __hip_bfloat16* __restrict__ hbuf, // [E][C][F]
    const __hip_bfloat16* __restrict__ W2t,  // [E][D][F]
    const float* __restrict__ b2,            // [E][D]
    const float* __restrict__ topval,        // [E][C]
    float* __restrict__ yo)                  // [E][C][D]
{
    __shared__ __align__(16) char smem[131072];
    const int tid = threadIdx.x;
    const int w = tid >> 6, lane = tid & 63;
    const int wr = w >> 2, wc = w & 3;
    const int fr = lane & 15, qlane = lane >> 4;

    const int bid = blockIdx.x;
    const int wg  = (bid & 7) * 32 + (bid >> 3);   // 256 % 8 == 0
    const int n0  = (wg & 3) * 256;
    const int m0  = ((wg >> 2) & 7) * 256;
    const int e   = wg >> 5;

    const char* Abase = (const char*)(hbuf + (size_t)e * C_CAP * F_FFN);
    const char* Bbase = (const char*)(W2t + (size_t)e * D_HID * F_FFN);

    const int cc = (tid & 7) ^ ((tid >> 3) & 7);
    int aog[2][2], bog[2][2];
#pragma unroll
    for (int hh = 0; hh < 2; ++hh)
#pragma unroll
        for (int j = 0; j < 2; ++j) {
            int r = m0 + hh * 128 + j * 64 + (tid >> 3);
            aog[hh][j] = (r * F_FFN + cc * 8) * 2;
            int n = n0 + hh * 128 + j * 64 + (tid >> 3);
            bog[hh][j] = (n * F_FFN + cc * 8) * 2;
        }

    const int arow = (wr * 128 + fr) * 128;
    const int brow = (wc * 64 + fr) * 128;
    const int kc0  = ((qlane)     ^ (lane & 7)) * 16;
    const int kc1  = ((4 + qlane) ^ (lane & 7)) * 16;

    bf16x8 aF[4][2], bF0[2][2], bF1[2][2];
    f32x4 acc[8][4];
#pragma unroll
    for (int mi = 0; mi < 8; ++mi)
#pragma unroll
        for (int ni = 0; ni < 4; ++ni) acc[mi][ni] = (f32x4){0.f, 0.f, 0.f, 0.f};

    GEMM_PROLOGUE();
    for (int t = 0; t < 64; ++t) GEMM_TILE(t, 64);   // NT = 4096/64

    // Epilogue: bias + gate weight, fp32; 4 ni stores cover 256 contiguous B.
    const int q4 = qlane * 4;
    float b2v[4];
#pragma unroll
    for (int ni = 0; ni < 4; ++ni)
        b2v[ni] = b2[e * D_HID + n0 + wc * 64 + ni * 16 + fr];
#pragma unroll
    for (int mi = 0; mi < 8; ++mi)
#pragma unroll
        for (int r = 0; r < 4; ++r) {
            const int row = m0 + wr * 128 + mi * 16 + q4 + r;
            const float g = topval[e * C_CAP + row];
            float* orow = yo + ((size_t)e * C_CAP + row) * D_HID + n0 + wc * 64;
#pragma unroll
            for (int ni = 0; ni < 4; ++ni)
                orow[ni * 16 + fr] = (acc[mi][ni][r] + b2v[ni]) * g;
        }
}

// ---------------------------------------------------------------------------
// Kernel 8: combine — out[t] = sum over inv[t] entries of yo rows.
// ---------------------------------------------------------------------------
__global__ __launch_bounds__(256) void combine_kernel(
    const float* __restrict__ yo, const int* __restrict__ cnt,
    const int* __restrict__ inv, float* __restrict__ out)
{
    const int t = blockIdx.x;
    const int n = cnt[t];
    const int c4 = threadIdx.x * 4;
    float4 a = {0.f, 0.f, 0.f, 0.f};
    for (int k = 0; k < n; ++k) {
        int ec = inv[t * E_EXP + k];
        float4 v = *(const float4*)(yo + (size_t)ec * D_HID + c4);
        a.x += v.x; a.y += v.y; a.z += v.z; a.w += v.w;
    }
    *(float4*)(out + (size_t)t * D_HID + c4) = a;
}

// ---------------------------------------------------------------------------
extern "C" void kernel_launch(void* const* d_in, const int* in_sizes, int n_in,
                              void* d_out, int out_size, void* d_ws, size_t ws_size,
                              hipStream_t stream) {
    const float* x  = (const float*)d_in[0];   // [T, D]
    const float* Wg = (const float*)d_in[1];   // [D, E]
    const float* W1 = (const float*)d_in[2];   // [E, D, F]
    const float* b1 = (const float*)d_in[3];   // [E, F]
    const float* W2 = (const float*)d_in[4];   // [E, F, D]
    const float* b2 = (const float*)d_in[5];   // [E, D]
    float* out = (float*)d_out;                // [T*D] out ++ [1] aux

    // Workspace layout
    char* p = (char*)d_ws;
    float* gatesT = (float*)p;            p += (size_t)E_EXP * T_TOK * 4;      // 256 KB
    int*   topidx = (int*)p;              p += (size_t)E_EXP * C_CAP * 4;      // 64 KB
    float* topval = (float*)p;            p += (size_t)E_EXP * C_CAP * 4;      // 64 KB
    int*   cnt    = (int*)p;              p += (size_t)T_TOK * 4;              // 32 KB
    int*   inv    = (int*)p;              p += (size_t)T_TOK * E_EXP * 4;      // 256 KB
    __hip_bfloat16* x_bf = (__hip_bfloat16*)p;  p += (size_t)T_TOK * D_HID * 2;         // 16.8 MB
    __hip_bfloat16* W1t  = (__hip_bfloat16*)p;  p += (size_t)E_EXP * D_HID * F_FFN * 2; // 67 MB
    __hip_bfloat16* W2t  = (__hip_bfloat16*)p;  p += (size_t)E_EXP * D_HID * F_FFN * 2; // 67 MB
    __hip_bfloat16* hbuf = (__hip_bfloat16*)p;  p += (size_t)E_EXP * C_CAP * F_FFN * 2; // 134 MB
    // yo aliases W1t (dead after gemm1; gemm2 writes yo, combine reads it).
    float* yo = (float*)W1t;   // E*C*D*4 = 67 MB, exactly W1t's size

    hipMemsetAsync(cnt, 0, (size_t)T_TOK * 4, stream);

    gating_kernel<<<T_TOK / 4, 256, 0, stream>>>(x, Wg, gatesT);
    aux_kernel<<<1, 256, 0, stream>>>(gatesT, out + (size_t)T_TOK * D_HID);
    topk_kernel<<<E_EXP, 1024, 0, stream>>>(gatesT, topidx, topval, cnt, inv);

    // bf16 conversions / weight transposes
    cvt_bf16_kernel<<<(T_TOK * D_HID / 4 + 255) / 256, 256, 0, stream>>>(
        x, x_bf, T_TOK * D_HID / 4);
    {
        dim3 g(F_FFN / 64, D_HID / 64, E_EXP);   // W1 [D,F] -> W1t [F,D]
        transpose_bf16_kernel<<<g, 256, 0, stream>>>(W1, W1t, D_HID, F_FFN);
    }
    {
        dim3 g(D_HID / 64, F_FFN / 64, E_EXP);   // W2 [F,D] -> W2t [D,F]
        transpose_bf16_kernel<<<g, 256, 0, stream>>>(W2, W2t, F_FFN, D_HID);
    }

    // Batched expert FFN: 256x256 8-phase MFMA GEMMs
    gemm1_kernel<<<1024, 512, 0, stream>>>(x_bf, W1t, b1, topidx, hbuf);
    gemm2_kernel<<<256, 512, 0, stream>>>(hbuf, W2t, b2, topval, yo);
    combine_kernel<<<T_TOK, 256, 0, stream>>>(yo, cnt, inv, out);
}

// Round 2
// 700.161 us; speedup vs baseline: 1.4554x; 1.1900x over previous
//
#include <hip/hip_runtime.h>
#include <hip/hip_bf16.h>

// Problem constants
#define T_TOK 8192
#define E_EXP 8
#define D_HID 1024
#define F_FFN 4096
#define C_CAP 2048   // T * 2.0 / E

typedef __attribute__((ext_vector_type(8))) short bf16x8;  // 8 bf16 (4 VGPRs)
typedef __attribute__((ext_vector_type(4))) float f32x4;   // 4 fp32 acc

// Async global->LDS, 16 B per lane. LDS dest is wave-uniform base + lane*16;
// source address may be per-lane (gather OK).
__device__ __forceinline__ void load_lds16(const void* g, void* l) {
    __builtin_amdgcn_global_load_lds(
        (const __attribute__((address_space(1))) unsigned int*)g,
        (__attribute__((address_space(3))) unsigned int*)l, 16, 0, 0);
}

// gelu(v) = v * sigmoid(1.595769 v + 0.0713548 v^3); __expf -> v_exp_f32.
__device__ __forceinline__ float gelu_fast(float v) {
    float z = v * (1.5957691216057308f + 0.07135481627f * v * v);
    return v / (1.0f + __expf(-z));
}

// ---------------------------------------------------------------------------
// Kernel 1: router gating (fp32 exact) + fused x->bf16 convert + aux const.
// One wave per token. aux = E*(C/T)*sum_e mean_t gates = E*(C/T) exactly,
// since softmax rows sum to 1 (ref computes 2.0 +- 1e-7; tol is 9.8e-3).
// ---------------------------------------------------------------------------
__global__ __launch_bounds__(256) void gating_kernel(
    const float* __restrict__ x, const float* __restrict__ Wg,
    float* __restrict__ gatesT, __hip_bfloat16* __restrict__ xbf,
    float* __restrict__ aux_out)
{
    const int token = blockIdx.x * 4 + (threadIdx.x >> 6);
    const int lane  = threadIdx.x & 63;
    if (token == 0 && lane == 0)
        aux_out[0] = (float)E_EXP * (float)C_CAP / (float)T_TOK;   // == 2.0f
    const float* xr = x + (size_t)token * D_HID;

    float acc[E_EXP];
#pragma unroll
    for (int e = 0; e < E_EXP; ++e) acc[e] = 0.0f;

#pragma unroll
    for (int it = 0; it < 4; ++it) {
        const int c4 = it * 64 + lane;               // float4 index in row
        float4 v = ((const float4*)xr)[c4];
        float vv[4] = {v.x, v.y, v.z, v.w};
        union { __hip_bfloat16 h[4]; short4 s; } u;
#pragma unroll
        for (int j = 0; j < 4; ++j) u.h[j] = __float2bfloat16(vv[j]);
        ((short4*)(xbf + (size_t)token * D_HID))[c4] = u.s;
        const float* wr0 = Wg + (size_t)c4 * 4 * E_EXP;
#pragma unroll
        for (int j = 0; j < 4; ++j)
#pragma unroll
            for (int e = 0; e < E_EXP; ++e) acc[e] += vv[j] * wr0[j * E_EXP + e];
    }
#pragma unroll
    for (int e = 0; e < E_EXP; ++e) {
        for (int off = 32; off; off >>= 1) acc[e] += __shfl_down(acc[e], off);
    }
    if (lane == 0) {
        float m = acc[0];
#pragma unroll
        for (int e = 1; e < E_EXP; ++e) m = fmaxf(m, acc[e]);
        float ex[E_EXP];
        float s = 0.0f;
#pragma unroll
        for (int e = 0; e < E_EXP; ++e) { ex[e] = expf(acc[e] - m); s += ex[e]; }
        float inv = 1.0f / s;
#pragma unroll
        for (int e = 0; e < E_EXP; ++e) gatesT[(size_t)e * T_TOK + token] = ex[e] * inv;
    }
}

// ---------------------------------------------------------------------------
// Kernel 3: exact per-expert top-C via radix-select + 2048-key bitonic sort.
// Same 64-bit keys as the full-sort version => bit-identical selection and
// jax tie-break. Radix: 8 passes of 8 bits find the exact 2048th-largest
// key; all keys >= thr (exactly C_CAP, keys unique) are compacted and sorted
// descending with a 66-pass bitonic on 2048 elements (vs 91 passes on 8192).
// Also builds the token -> (expert, slot) inverse map for the combine pass.
// ---------------------------------------------------------------------------
__global__ __launch_bounds__(1024) void topk_kernel(
    const float* __restrict__ gatesT, int* __restrict__ topidx,
    float* __restrict__ topval, int* __restrict__ cnt, int* __restrict__ inv)
{
    __shared__ unsigned long long keys[T_TOK];   // 64 KB
    __shared__ unsigned long long sel[C_CAP];    // 16 KB
    __shared__ unsigned int hist[256];
    __shared__ unsigned int cum[256];
    __shared__ unsigned int bc_v, bc_r;
    __shared__ unsigned int selcnt;

    const int e   = blockIdx.x;
    const int tid = threadIdx.x;
    const float* row = gatesT + (size_t)e * T_TOK;

    for (int i = tid; i < T_TOK; i += 1024) {
        unsigned int b = __float_as_uint(row[i]);
        b = (b & 0x80000000u) ? ~b : (b | 0x80000000u);
        keys[i] = ((unsigned long long)b << 32) | (unsigned int)(T_TOK - 1 - i);
    }
    if (tid == 0) selcnt = 0;
    __syncthreads();

    // --- radix-select: exact C_CAP-th largest key ---
    unsigned long long prefix = 0ull, mask = 0ull;
    unsigned int rank = C_CAP;
    for (int byte = 7; byte >= 0; --byte) {
        if (tid < 256) hist[tid] = 0;
        __syncthreads();
        const int sh = byte * 8;
        for (int i = tid; i < T_TOK; i += 1024) {
            unsigned long long k = keys[i];
            if ((k & mask) == prefix)
                atomicAdd(&hist[(unsigned int)((k >> sh) & 255ull)], 1u);
        }
        __syncthreads();
        if (tid < 256) cum[tid] = hist[tid];
        __syncthreads();
        // suffix-sum: cum[v] = count of candidate keys with byte >= v
        for (int off = 1; off < 256; off <<= 1) {
            unsigned int add = 0;
            if (tid < 256 && tid + off < 256) add = cum[tid + off];
            __syncthreads();
            if (tid < 256) cum[tid] += add;
            __syncthreads();
        }
        if (tid < 256) {
            unsigned int ge = cum[tid];
            unsigned int gt = (tid < 255) ? cum[tid + 1] : 0u;
            if (ge >= rank && gt < rank) { bc_v = (unsigned int)tid; bc_r = rank - gt; }
        }
        __syncthreads();
        prefix |= ((unsigned long long)bc_v) << sh;
        mask   |= (0xFFull << sh);
        rank = bc_r;
        __syncthreads();
    }
    const unsigned long long thr = prefix;   // exact C_CAP-th largest key

    // --- compact the exactly-C_CAP keys >= thr (order irrelevant pre-sort) ---
    for (int i = tid; i < T_TOK; i += 1024) {
        unsigned long long k = keys[i];
        if (k >= thr) sel[atomicAdd(&selcnt, 1u)] = k;
    }
    __syncthreads();

    // --- bitonic sort sel[2048] descending (same network as before) ---
    for (int k = 2; k <= C_CAP; k <<= 1) {
        for (int j = k >> 1; j > 0; j >>= 1) {
            for (int i = tid; i < C_CAP; i += 1024) {
                int p = i ^ j;
                if (p > i) {
                    bool desc = ((i & k) == 0);
                    unsigned long long a = sel[i];
                    unsigned long long b = sel[p];
                    bool sw = desc ? (a < b) : (a > b);
                    if (sw) { sel[i] = b; sel[p] = a; }
                }
            }
            __syncthreads();
        }
    }

    for (int c = tid; c < C_CAP; c += 1024) {
        unsigned long long kk = sel[c];
        int idx = T_TOK - 1 - (int)(kk & 0xFFFFFFFFu);
        unsigned int b = (unsigned int)(kk >> 32);
        b = (b & 0x80000000u) ? (b & 0x7FFFFFFFu) : ~b;
        topidx[e * C_CAP + c] = idx;
        topval[e * C_CAP + c] = __uint_as_float(b);
        int slot = atomicAdd(&cnt[idx], 1);   // <=8 entries per token (1/expert)
        inv[idx * E_EXP + slot] = e * C_CAP + c;
    }
}

// ---------------------------------------------------------------------------
// Kernel 5: per-expert transpose+convert: [E][R][Cn] fp32 -> [E][Cn][R] bf16.
// ---------------------------------------------------------------------------
__global__ __launch_bounds__(256) void transpose_bf16_kernel(
    const float* __restrict__ in, __hip_bfloat16* __restrict__ out,
    int R, int Cn)
{
    __shared__ float tile[64][65];
    const int e = blockIdx.z;
    in  += (size_t)e * R * Cn;
    out += (size_t)e * R * Cn;
    const int c0 = blockIdx.x * 64, r0 = blockIdx.y * 64;
    const int tid = threadIdx.x;

    const int lr = tid >> 4, lc4 = (tid & 15) * 4;
#pragma unroll
    for (int it = 0; it < 4; ++it) {
        int r = lr + it * 16;
        float4 v = *(const float4*)(in + (size_t)(r0 + r) * Cn + c0 + lc4);
        tile[r][lc4 + 0] = v.x; tile[r][lc4 + 1] = v.y;
        tile[r][lc4 + 2] = v.z; tile[r][lc4 + 3] = v.w;
    }
    __syncthreads();

    const int ocb = tid >> 3, j0 = (tid & 7) * 8;
#pragma unroll
    for (int it = 0; it < 2; ++it) {
        int oc = ocb + it * 32;
        union { __hip_bfloat16 h[8]; uint4 v; } u;
#pragma unroll
        for (int j = 0; j < 8; ++j) u.h[j] = __float2bfloat16(tile[j0 + j][oc]);
        *(uint4*)(out + (size_t)(c0 + oc) * R + r0 + j0) = u.v;
    }
}

// ===========================================================================
// 256x256 8-phase GEMM template (plain-HIP port of the verified m201/HK
// schedule): BK=64, 8 waves (2M x 4N), 512 threads, 128 KiB LDS dbuf,
// XOR-swizzled LDS (chunk ^= row&7, involution; linear global_load_lds dest
// with inverse-swizzled per-lane SOURCE), counted vmcnt(4) once per K-tile,
// setprio(1) around each 16-MFMA cluster.
//
// Stage schedule per K-tile u:
//   ph0: stage Alo(u+1)   ph1: stage Ahi(u+1)
//   ph2: stage Blo(u+2)   ph3: stage Bhi(u+2), then vmcnt(4), barrier
// ===========================================================================

#define BARS do { __builtin_amdgcn_s_barrier(); __builtin_amdgcn_sched_barrier(0); } while (0)
#define WLG  do { asm volatile("s_waitcnt lgkmcnt(0)" ::: "memory"); __builtin_amdgcn_sched_barrier(0); } while (0)
#define VMC4 asm volatile("s_waitcnt vmcnt(4)" ::: "memory")
#define VMC0 asm volatile("s_waitcnt vmcnt(0)" ::: "memory")

#define G_STAGE_A(hh, s) do { int b_ = (((s) & 1) << 15) + ((hh) << 14) + (w << 10); \
    load_lds16(Abase + (size_t)(aog[hh][0] + (s) * 128), smem + b_); \
    load_lds16(Abase + (size_t)(aog[hh][1] + (s) * 128), smem + b_ + 8192); } while (0)
#define G_STAGE_B(hh, s) do { int b_ = 65536 + (((s) & 1) << 15) + ((hh) << 14) + (w << 10); \
    load_lds16(Bbase + (size_t)(bog[hh][0] + (s) * 128), smem + b_); \
    load_lds16(Bbase + (size_t)(bog[hh][1] + (s) * 128), smem + b_ + 8192); } while (0)

#define READ_A(mh) do { _Pragma("unroll") for (int mi = 0; mi < 4; ++mi) { \
    aF[mi][0] = *(const bf16x8*)(Ab + (arow + (mh) * 8192 + mi * 2048 + kc0)); \
    aF[mi][1] = *(const bf16x8*)(Ab + (arow + (mh) * 8192 + mi * 2048 + kc1)); } } while (0)
#define READ_B(nh, dst) do { _Pragma("unroll") for (int ni = 0; ni < 2; ++ni) { \
    dst[ni][0] = *(const bf16x8*)(Bb + (brow + (nh) * 4096 + ni * 2048 + kc0)); \
    dst[ni][1] = *(const bf16x8*)(Bb + (brow + (nh) * 4096 + ni * 2048 + kc1)); } } while (0)

#define QUAD(mh, nh, BF) do { \
    __builtin_amdgcn_s_setprio(1); \
    _Pragma("unroll") for (int mi = 0; mi < 4; ++mi) \
    _Pragma("unroll") for (int ni = 0; ni < 2; ++ni) { \
        acc[(mh)*4+mi][(nh)*2+ni] = __builtin_amdgcn_mfma_f32_16x16x32_bf16( \
            aF[mi][0], BF[ni][0], acc[(mh)*4+mi][(nh)*2+ni], 0, 0, 0); \
        acc[(mh)*4+mi][(nh)*2+ni] = __builtin_amdgcn_mfma_f32_16x16x32_bf16( \
            aF[mi][1], BF[ni][1], acc[(mh)*4+mi][(nh)*2+ni], 0, 0, 0); } \
    __builtin_amdgcn_s_setprio(0); } while (0)

#define GEMM_PROLOGUE() do { \
    G_STAGE_A(0, 0); G_STAGE_A(1, 0); G_STAGE_B(0, 0); G_STAGE_B(1, 0); \
    G_STAGE_B(0, 1); G_STAGE_B(1, 1); \
    VMC4; BARS; } while (0)

#define GEMM_TILE(t, NT) do { \
    const char* Ab = smem + (((t) & 1) << 15); \
    const char* Bb = smem + 65536 + (((t) & 1) << 15); \
    /* phase 0 */ \
    READ_A(0); READ_B(0, bF0); \
    if ((t) + 1 < (NT)) G_STAGE_A(0, (t) + 1); \
    BARS; WLG; QUAD(0, 0, bF0); BARS; \
    /* phase 1 */ \
    READ_B(1, bF1); \
    if ((t) + 1 < (NT)) G_STAGE_A(1, (t) + 1); \
    BARS; WLG; QUAD(0, 1, bF1); BARS; \
    /* phase 2 */ \
    READ_A(1); \
    if ((t) + 2 < (NT)) G_STAGE_B(0, (t) + 2); \
    BARS; WLG; QUAD(1, 1, bF1); BARS; \
    /* phase 3 */ \
    if ((t) + 2 < (NT)) G_STAGE_B(1, (t) + 2); \
    BARS; WLG; QUAD(1, 0, bF0); \
    if ((t) + 2 < (NT)) { VMC4; } else { VMC0; } \
    BARS; } while (0)

// ---------------------------------------------------------------------------
// Kernel 6: GEMM1 (all experts): h[e] = gelu(gather(x)[C,D] @ W1t[e]^T + b1[e])
// M=C=2048, N=F=4096, K=D=1024. Grid 1024 blocks x 512 thr.
// Block order m-fastest within expert: 32 concurrent blocks/XCD share a
// 4-n-panel B slice (2 MB, fits 4 MiB L2) instead of 16 panels (8.4 MB).
// ---------------------------------------------------------------------------
__global__ __launch_bounds__(512, 2) void gemm1_kernel(
    const __hip_bfloat16* __restrict__ xb,   // [T][D]
    const __hip_bfloat16* __restrict__ W1t,  // [E][F][D]
    const float* __restrict__ b1,            // [E][F]
    const int* __restrict__ topidx,          // [E][C]
    __hip_bfloat16* __restrict__ hbuf)       // [E][C][F]
{
    __shared__ __align__(16) char smem[131072];   // [A0|A1|B0|B1] x 32 KiB
    const int tid = threadIdx.x;
    const int w = tid >> 6, lane = tid & 63;
    const int wr = w >> 2, wc = w & 3;
    const int fr = lane & 15, qlane = lane >> 4;

    // XCD-bijective swizzle (1024 % 8 == 0), m-fastest within expert
    const int bid = blockIdx.x;
    const int wg  = (bid & 7) * 128 + (bid >> 3);
    const int m0  = (wg & 7) * 256;
    const int n0  = ((wg >> 3) & 15) * 256;
    const int e   = wg >> 7;

    const char* Abase = (const char*)xb;
    const char* Bbase = (const char*)(W1t + (size_t)e * F_FFN * D_HID);

    // staging source byte offsets (inverse-swizzled column chunk)
    const int cc = (tid & 7) ^ ((tid >> 3) & 7);
    int aog[2][2], bog[2][2];
#pragma unroll
    for (int hh = 0; hh < 2; ++hh)
#pragma unroll
        for (int j = 0; j < 2; ++j) {
            int r   = m0 + hh * 128 + j * 64 + (tid >> 3);
            int tok = topidx[e * C_CAP + r];
            aog[hh][j] = (tok * D_HID + cc * 8) * 2;
            int n = n0 + hh * 128 + j * 64 + (tid >> 3);
            bog[hh][j] = (n * D_HID + cc * 8) * 2;
        }

    const int arow = (wr * 128 + fr) * 128;
    const int brow = (wc * 64 + fr) * 128;
    const int kc0  = ((qlane)     ^ (lane & 7)) * 16;
    const int kc1  = ((4 + qlane) ^ (lane & 7)) * 16;

    bf16x8 aF[4][2], bF0[2][2], bF1[2][2];
    f32x4 acc[8][4];
#pragma unroll
    for (int mi = 0; mi < 8; ++mi)
#pragma unroll
        for (int ni = 0; ni < 4; ++ni) acc[mi][ni] = (f32x4){0.f, 0.f, 0.f, 0.f};

    GEMM_PROLOGUE();
    for (int t = 0; t < 16; ++t) GEMM_TILE(t, 16);   // NT = 1024/64

    // Epilogue: bias + gelu -> bf16 via full-LDS transpose (exactly 128 KiB).
    // Writes: 2B scattered into LDS with row-XOR swizzle (~4-way, cheap).
    // Readback: ds_read_b128, half-wave covers a full 512 B output row.
    const int q4 = qlane * 4;
    float b1v[4];
#pragma unroll
    for (int ni = 0; ni < 4; ++ni)
        b1v[ni] = b1[e * F_FFN + n0 + wc * 64 + ni * 16 + fr];
    // last GEMM_TILE ended with VMC0 + barrier: LDS free to reuse
#pragma unroll
    for (int mi = 0; mi < 8; ++mi)
#pragma unroll
        for (int r = 0; r < 4; ++r) {
            const int row = wr * 128 + mi * 16 + q4 + r;
            char* rb = smem + row * 512;
            const int sw = (row & 7) << 4;
#pragma unroll
            for (int ni = 0; ni < 4; ++ni) {
                const int col2 = (wc * 64 + ni * 16 + fr) * 2;
                *(__hip_bfloat16*)(rb + (col2 ^ sw)) =
                    __float2bfloat16(gelu_fast(acc[mi][ni][r] + b1v[ni]));
            }
        }
    __syncthreads();
#pragma unroll
    for (int it = 0; it < 16; ++it) {
        const int row = it * 16 + w * 2 + (lane >> 5);
        const int cb  = (lane & 31) * 16;
        uint4 v = *(const uint4*)(smem + row * 512 + (cb ^ ((row & 7) << 4)));
        char* gp = (char*)(hbuf + ((size_t)e * C_CAP + m0 + row) * F_FFN + n0) + cb;
        *(uint4*)gp = v;
    }
}

// ---------------------------------------------------------------------------
// Kernel 7: GEMM2 (all experts): yo[e][c] = (h[e] @ W2t[e]^T + b2[e]) * gate
// M=C=2048, N=D=1024, K=F=4096. Grid 256 blocks x 512 thr (1/CU).
// ---------------------------------------------------------------------------
__global__ __launch_bounds__(512, 2) void gemm2_kernel(
    const __hip_bfloat16* __restrict__ hbuf, // [E][C][F]
    const __hip_bfloat16* __restrict__ W2t,  // [E][D][F]
    const float* __restrict__ b2,            // [E][D]
    const float* __restrict__ topval,        // [E][C]
    float* __restrict__ yo)                  // [E][C][D]
{
    __shared__ __align__(16) char smem[131072];
    const int tid = threadIdx.x;
    const int w = tid >> 6, lane = tid & 63;
    const int wr = w >> 2, wc = w & 3;
    const int fr = lane & 15, qlane = lane >> 4;

    const int bid = blockIdx.x;
    const int wg  = (bid & 7) * 32 + (bid >> 3);   // 256 % 8 == 0
    const int n0  = (wg & 3) * 256;
    const int m0  = ((wg >> 2) & 7) * 256;
    const int e   = wg >> 5;

    const char* Abase = (const char*)(hbuf + (size_t)e * C_CAP * F_FFN);
    const char* Bbase = (const char*)(W2t + (size_t)e * D_HID * F_FFN);

    const int cc = (tid & 7) ^ ((tid >> 3) & 7);
    int aog[2][2], bog[2][2];
#pragma unroll
    for (int hh = 0; hh < 2; ++hh)
#pragma unroll
        for (int j = 0; j < 2; ++j) {
            int r = m0 + hh * 128 + j * 64 + (tid >> 3);
            aog[hh][j] = (r * F_FFN + cc * 8) * 2;
            int n = n0 + hh * 128 + j * 64 + (tid >> 3);
            bog[hh][j] = (n * F_FFN + cc * 8) * 2;
        }

    const int arow = (wr * 128 + fr) * 128;
    const int brow = (wc * 64 + fr) * 128;
    const int kc0  = ((qlane)     ^ (lane & 7)) * 16;
    const int kc1  = ((4 + qlane) ^ (lane & 7)) * 16;

    bf16x8 aF[4][2], bF0[2][2], bF1[2][2];
    f32x4 acc[8][4];
#pragma unroll
    for (int mi = 0; mi < 8; ++mi)
#pragma unroll
        for (int ni = 0; ni < 4; ++ni) acc[mi][ni] = (f32x4){0.f, 0.f, 0.f, 0.f};

    GEMM_PROLOGUE();
    for (int t = 0; t < 64; ++t) GEMM_TILE(t, 64);   // NT = 4096/64

    // Epilogue: bias + gate weight, fp32; 16-lane groups cover 64 B runs.
    const int q4 = qlane * 4;
    float b2v[4];
#pragma unroll
    for (int ni = 0; ni < 4; ++ni)
        b2v[ni] = b2[e * D_HID + n0 + wc * 64 + ni * 16 + fr];
#pragma unroll
    for (int mi = 0; mi < 8; ++mi)
#pragma unroll
        for (int r = 0; r < 4; ++r) {
            const int row = m0 + wr * 128 + mi * 16 + q4 + r;
            const float g = topval[e * C_CAP + row];
            float* orow = yo + ((size_t)e * C_CAP + row) * D_HID + n0 + wc * 64;
#pragma unroll
            for (int ni = 0; ni < 4; ++ni)
                orow[ni * 16 + fr] = (acc[mi][ni][r] + b2v[ni]) * g;
        }
}

// ---------------------------------------------------------------------------
// Kernel 8: combine — out[t] = sum over inv[t] entries of yo rows.
// ---------------------------------------------------------------------------
__global__ __launch_bounds__(256) void combine_kernel(
    const float* __restrict__ yo, const int* __restrict__ cnt,
    const int* __restrict__ inv, float* __restrict__ out)
{
    const int t = blockIdx.x;
    const int n = cnt[t];
    const int c4 = threadIdx.x * 4;
    float4 a = {0.f, 0.f, 0.f, 0.f};
    for (int k = 0; k < n; ++k) {
        int ec = inv[t * E_EXP + k];
        float4 v = *(const float4*)(yo + (size_t)ec * D_HID + c4);
        a.x += v.x; a.y += v.y; a.z += v.z; a.w += v.w;
    }
    *(float4*)(out + (size_t)t * D_HID + c4) = a;
}

// ---------------------------------------------------------------------------
extern "C" void kernel_launch(void* const* d_in, const int* in_sizes, int n_in,
                              void* d_out, int out_size, void* d_ws, size_t ws_size,
                              hipStream_t stream) {
    const float* x  = (const float*)d_in[0];   // [T, D]
    const float* Wg = (const float*)d_in[1];   // [D, E]
    const float* W1 = (const float*)d_in[2];   // [E, D, F]
    const float* b1 = (const float*)d_in[3];   // [E, F]
    const float* W2 = (const float*)d_in[4];   // [E, F, D]
    const float* b2 = (const float*)d_in[5];   // [E, D]
    float* out = (float*)d_out;                // [T*D] out ++ [1] aux

    // Workspace layout
    char* p = (char*)d_ws;
    float* gatesT = (float*)p;            p += (size_t)E_EXP * T_TOK * 4;      // 256 KB
    int*   topidx = (int*)p;              p += (size_t)E_EXP * C_CAP * 4;      // 64 KB
    float* topval = (float*)p;            p += (size_t)E_EXP * C_CAP * 4;      // 64 KB
    int*   cnt    = (int*)p;              p += (size_t)T_TOK * 4;              // 32 KB
    int*   inv    = (int*)p;              p += (size_t)T_TOK * E_EXP * 4;      // 256 KB
    __hip_bfloat16* x_bf = (__hip_bfloat16*)p;  p += (size_t)T_TOK * D_HID * 2;         // 16.8 MB
    __hip_bfloat16* W1t  = (__hip_bfloat16*)p;  p += (size_t)E_EXP * D_HID * F_FFN * 2; // 67 MB
    __hip_bfloat16* W2t  = (__hip_bfloat16*)p;  p += (size_t)E_EXP * D_HID * F_FFN * 2; // 67 MB
    __hip_bfloat16* hbuf = (__hip_bfloat16*)p;  p += (size_t)E_EXP * C_CAP * F_FFN * 2; // 134 MB
    // yo aliases W1t (dead after gemm1; gemm2 writes yo, combine reads it).
    float* yo = (float*)W1t;   // E*C*D*4 = 67 MB, exactly W1t's size

    hipMemsetAsync(cnt, 0, (size_t)T_TOK * 4, stream);

    // gating fuses x->bf16 convert and writes the (constant) aux loss
    gating_kernel<<<T_TOK / 4, 256, 0, stream>>>(
        x, Wg, gatesT, x_bf, out + (size_t)T_TOK * D_HID);
    topk_kernel<<<E_EXP, 1024, 0, stream>>>(gatesT, topidx, topval, cnt, inv);

    // weight transposes (fp32 -> bf16)
    {
        dim3 g(F_FFN / 64, D_HID / 64, E_EXP);   // W1 [D,F] -> W1t [F,D]
        transpose_bf16_kernel<<<g, 256, 0, stream>>>(W1, W1t, D_HID, F_FFN);
    }
    {
        dim3 g(D_HID / 64, F_FFN / 64, E_EXP);   // W2 [F,D] -> W2t [D,F]
        transpose_bf16_kernel<<<g, 256, 0, stream>>>(W2, W2t, F_FFN, D_HID);
    }

    // Batched expert FFN: 256x256 8-phase MFMA GEMMs
    gemm1_kernel<<<1024, 512, 0, stream>>>(x_bf, W1t, b1, topidx, hbuf);
    gemm2_kernel<<<256, 512, 0, stream>>>(hbuf, W2t, b2, topval, yo);
    combine_kernel<<<T_TOK, 256, 0, stream>>>(yo, cnt, inv, out);
}

// Round 3
// 664.653 us; speedup vs baseline: 1.5331x; 1.0534x over previous
//
#include <hip/hip_runtime.h>
#include <hip/hip_bf16.h>

// Problem constants
#define T_TOK 8192
#define E_EXP 8
#define D_HID 1024
#define F_FFN 4096
#define C_CAP 2048   // T * 2.0 / E

typedef __attribute__((ext_vector_type(8))) short bf16x8;  // 8 bf16 (4 VGPRs)
typedef __attribute__((ext_vector_type(4))) float f32x4;   // 4 fp32 acc

// Async global->LDS, 16 B per lane. LDS dest is wave-uniform base + lane*16;
// source address may be per-lane (gather OK).
__device__ __forceinline__ void load_lds16(const void* g, void* l) {
    __builtin_amdgcn_global_load_lds(
        (const __attribute__((address_space(1))) unsigned int*)g,
        (__attribute__((address_space(3))) unsigned int*)l, 16, 0, 0);
}

// gelu(v) = v * sigmoid(1.595769 v + 0.0713548 v^3); __expf -> v_exp_f32.
__device__ __forceinline__ float gelu_fast(float v) {
    float z = v * (1.5957691216057308f + 0.07135481627f * v * v);
    return v / (1.0f + __expf(-z));
}

// ---------------------------------------------------------------------------
// Kernel 1: router gating (fp32 exact) + fused x->bf16 convert + aux const.
// One wave per token. aux = E*(C/T)*sum_e mean_t gates = E*(C/T) exactly,
// since softmax rows sum to 1 (ref computes 2.0 +- 1e-7; tol is 9.8e-3).
// ---------------------------------------------------------------------------
__global__ __launch_bounds__(256) void gating_kernel(
    const float* __restrict__ x, const float* __restrict__ Wg,
    float* __restrict__ gatesT, __hip_bfloat16* __restrict__ xbf,
    float* __restrict__ aux_out)
{
    const int token = blockIdx.x * 4 + (threadIdx.x >> 6);
    const int lane  = threadIdx.x & 63;
    if (token == 0 && lane == 0)
        aux_out[0] = (float)E_EXP * (float)C_CAP / (float)T_TOK;   // == 2.0f
    const float* xr = x + (size_t)token * D_HID;

    float acc[E_EXP];
#pragma unroll
    for (int e = 0; e < E_EXP; ++e) acc[e] = 0.0f;

#pragma unroll
    for (int it = 0; it < 4; ++it) {
        const int c4 = it * 64 + lane;               // float4 index in row
        float4 v = ((const float4*)xr)[c4];
        float vv[4] = {v.x, v.y, v.z, v.w};
        union { __hip_bfloat16 h[4]; short4 s; } u;
#pragma unroll
        for (int j = 0; j < 4; ++j) u.h[j] = __float2bfloat16(vv[j]);
        ((short4*)(xbf + (size_t)token * D_HID))[c4] = u.s;
        const float* wr0 = Wg + (size_t)c4 * 4 * E_EXP;
#pragma unroll
        for (int j = 0; j < 4; ++j)
#pragma unroll
            for (int e = 0; e < E_EXP; ++e) acc[e] += vv[j] * wr0[j * E_EXP + e];
    }
#pragma unroll
    for (int e = 0; e < E_EXP; ++e) {
        for (int off = 32; off; off >>= 1) acc[e] += __shfl_down(acc[e], off);
    }
    if (lane == 0) {
        float m = acc[0];
#pragma unroll
        for (int e = 1; e < E_EXP; ++e) m = fmaxf(m, acc[e]);
        float ex[E_EXP];
        float s = 0.0f;
#pragma unroll
        for (int e = 0; e < E_EXP; ++e) { ex[e] = expf(acc[e] - m); s += ex[e]; }
        float inv = 1.0f / s;
#pragma unroll
        for (int e = 0; e < E_EXP; ++e) gatesT[(size_t)e * T_TOK + token] = ex[e] * inv;
    }
}

// ---------------------------------------------------------------------------
// Kernel 3: exact per-expert top-C via register radix-select, NO sort.
// Same 64-bit keys (float-transform<<32 | (T-1-i)) => the selected SET is
// bit-identical to jax top_k incl. tie-break. Output order within an expert
// is irrelevant to the final out[] (topidx/topval/inv stay consistent under
// any permutation; combine sums per token). Keys live in registers
// (8/thread); bucket-walk suffix-scan runs in wave 0 via shuffles.
// ---------------------------------------------------------------------------
__global__ __launch_bounds__(1024) void topk_kernel(
    const float* __restrict__ gatesT, int* __restrict__ topidx,
    float* __restrict__ topval, int* __restrict__ cnt, int* __restrict__ inv)
{
    __shared__ unsigned int hist[256];
    __shared__ unsigned int bc_v, bc_r;
    __shared__ unsigned int selcnt;

    const int e    = blockIdx.x;
    const int tid  = threadIdx.x;
    const int lane = tid & 63;
    const float* row = gatesT + (size_t)e * T_TOK;

    unsigned long long kreg[8];
#pragma unroll
    for (int p = 0; p < 8; ++p) {
        int i = tid + p * 1024;
        unsigned int b = __float_as_uint(row[i]);
        b = (b & 0x80000000u) ? ~b : (b | 0x80000000u);
        kreg[p] = ((unsigned long long)b << 32) | (unsigned int)(T_TOK - 1 - i);
    }
    if (tid == 0) selcnt = 0;

    unsigned long long prefix = 0ull, mask = 0ull;
    unsigned int rank = C_CAP;
    for (int byte = 7; byte >= 0; --byte) {
        if (tid < 256) hist[tid] = 0;
        __syncthreads();
        const int sh = byte * 8;
#pragma unroll
        for (int p = 0; p < 8; ++p) {
            unsigned long long k = kreg[p];
            if ((k & mask) == prefix)
                atomicAdd(&hist[(unsigned int)((k >> sh) & 255ull)], 1u);
        }
        __syncthreads();
        if (tid < 64) {
            // per-lane 4 buckets; within-lane suffix then cross-lane suffix
            unsigned int v0 = hist[tid * 4], v1 = hist[tid * 4 + 1];
            unsigned int v2 = hist[tid * 4 + 2], v3 = hist[tid * 4 + 3];
            unsigned int s3 = v3, s2 = v2 + s3, s1 = v1 + s2, s0 = v0 + s1;
            unsigned int t = s0;
#pragma unroll
            for (int off = 1; off < 64; off <<= 1) {
                unsigned int u = __shfl_down(t, off);
                if (lane + off < 64) t += u;
            }
            const unsigned int suf = t - s0;   // count in buckets of lanes > tid
            unsigned int ge[4] = {s0 + suf, s1 + suf, s2 + suf, s3 + suf};
            unsigned int gt[4] = {s1 + suf, s2 + suf, s3 + suf, suf};
#pragma unroll
            for (int j = 0; j < 4; ++j)
                if (ge[j] >= rank && gt[j] < rank) {
                    bc_v = (unsigned int)(tid * 4 + j); bc_r = rank - gt[j];
                }
        }
        __syncthreads();
        prefix |= ((unsigned long long)bc_v) << sh;
        mask   |= (0xFFull << sh);
        rank = bc_r;
        __syncthreads();
    }
    const unsigned long long thr = prefix;   // exact C_CAP-th largest key

    // compact directly to outputs (exactly C_CAP keys >= thr; keys unique)
#pragma unroll
    for (int p = 0; p < 8; ++p) {
        unsigned long long k = kreg[p];
        if (k >= thr) {
            int c = (int)atomicAdd(&selcnt, 1u);
            int idx = T_TOK - 1 - (int)(k & 0xFFFFFFFFull);
            unsigned int b = (unsigned int)(k >> 32);
            b = (b & 0x80000000u) ? (b & 0x7FFFFFFFu) : ~b;
            topidx[e * C_CAP + c] = idx;
            topval[e * C_CAP + c] = __uint_as_float(b);
            int slot = atomicAdd(&cnt[idx], 1);   // <=8 entries per token
            inv[idx * E_EXP + slot] = e * C_CAP + c;
        }
    }
}

// ---------------------------------------------------------------------------
// Kernel 5: per-expert transpose+convert: [E][R][Cn] fp32 -> [E][Cn][R] bf16.
// ---------------------------------------------------------------------------
__global__ __launch_bounds__(256) void transpose_bf16_kernel(
    const float* __restrict__ in, __hip_bfloat16* __restrict__ out,
    int R, int Cn)
{
    __shared__ float tile[64][65];
    const int e = blockIdx.z;
    in  += (size_t)e * R * Cn;
    out += (size_t)e * R * Cn;
    const int c0 = blockIdx.x * 64, r0 = blockIdx.y * 64;
    const int tid = threadIdx.x;

    const int lr = tid >> 4, lc4 = (tid & 15) * 4;
#pragma unroll
    for (int it = 0; it < 4; ++it) {
        int r = lr + it * 16;
        float4 v = *(const float4*)(in + (size_t)(r0 + r) * Cn + c0 + lc4);
        tile[r][lc4 + 0] = v.x; tile[r][lc4 + 1] = v.y;
        tile[r][lc4 + 2] = v.z; tile[r][lc4 + 3] = v.w;
    }
    __syncthreads();

    const int ocb = tid >> 3, j0 = (tid & 7) * 8;
#pragma unroll
    for (int it = 0; it < 2; ++it) {
        int oc = ocb + it * 32;
        union { __hip_bfloat16 h[8]; uint4 v; } u;
#pragma unroll
        for (int j = 0; j < 8; ++j) u.h[j] = __float2bfloat16(tile[j0 + j][oc]);
        *(uint4*)(out + (size_t)(c0 + oc) * R + r0 + j0) = u.v;
    }
}

// ===========================================================================
// 256x256 8-phase GEMM template (m201/HK schedule, verified rounds 1-2):
// BK=64, 8 waves (2M x 4N), 512 threads, 128 KiB LDS dbuf, XOR-swizzled LDS
// (chunk ^= row&7; linear global_load_lds dest + inverse-swizzled source),
// counted vmcnt(4) once per K-tile, setprio(1) around 16-MFMA clusters.
// Staging macros are parameters so gemm1 can chain multiple output tiles
// through one unbroken pipeline (source offsets differ; bookkeeping doesn't).
// ===========================================================================

#define BARS do { __builtin_amdgcn_s_barrier(); __builtin_amdgcn_sched_barrier(0); } while (0)
#define WLG  do { asm volatile("s_waitcnt lgkmcnt(0)" ::: "memory"); __builtin_amdgcn_sched_barrier(0); } while (0)
#define VMC4 asm volatile("s_waitcnt vmcnt(4)" ::: "memory")
#define VMC0 asm volatile("s_waitcnt vmcnt(0)" ::: "memory")

// gemm2 staging: source offset s*128 B along K
#define STG2_A(hh, s) do { int b_ = (((s) & 1) << 15) + ((hh) << 14) + (w << 10); \
    load_lds16(Abase + (size_t)(aog[hh][0] + (s) * 128), smem + b_); \
    load_lds16(Abase + (size_t)(aog[hh][1] + (s) * 128), smem + b_ + 8192); } while (0)
#define STG2_B(hh, s) do { int b_ = 65536 + (((s) & 1) << 15) + ((hh) << 14) + (w << 10); \
    load_lds16(Bbase + (size_t)(bog[hh][0] + (s) * 128), smem + b_); \
    load_lds16(Bbase + (size_t)(bog[hh][1] + (s) * 128), smem + b_ + 8192); } while (0)

// gemm1 chained staging: K wraps every 16 tiles (K=1024); B advances one
// 256-row n-panel (256*D_HID*2 = 524288 B) per 16-tile segment; A repeats.
#define STG1_A(hh, s) do { int b_ = (((s) & 1) << 15) + ((hh) << 14) + (w << 10); \
    int o_ = ((s) & 15) * 128; \
    load_lds16(Abase + (size_t)(aog[hh][0] + o_), smem + b_); \
    load_lds16(Abase + (size_t)(aog[hh][1] + o_), smem + b_ + 8192); } while (0)
#define STG1_B(hh, s) do { int b_ = 65536 + (((s) & 1) << 15) + ((hh) << 14) + (w << 10); \
    int o_ = ((s) >> 4) * 524288 + ((s) & 15) * 128; \
    load_lds16(Bbase + (size_t)(bog[hh][0] + o_), smem + b_); \
    load_lds16(Bbase + (size_t)(bog[hh][1] + o_), smem + b_ + 8192); } while (0)

#define READ_A(mh) do { _Pragma("unroll") for (int mi = 0; mi < 4; ++mi) { \
    aF[mi][0] = *(const bf16x8*)(Ab + (arow + (mh) * 8192 + mi * 2048 + kc0)); \
    aF[mi][1] = *(const bf16x8*)(Ab + (arow + (mh) * 8192 + mi * 2048 + kc1)); } } while (0)
#define READ_B(nh, dst) do { _Pragma("unroll") for (int ni = 0; ni < 2; ++ni) { \
    dst[ni][0] = *(const bf16x8*)(Bb + (brow + (nh) * 4096 + ni * 2048 + kc0)); \
    dst[ni][1] = *(const bf16x8*)(Bb + (brow + (nh) * 4096 + ni * 2048 + kc1)); } } while (0)

#define QUAD(mh, nh, BF) do { \
    __builtin_amdgcn_s_setprio(1); \
    _Pragma("unroll") for (int mi = 0; mi < 4; ++mi) \
    _Pragma("unroll") for (int ni = 0; ni < 2; ++ni) { \
        acc[(mh)*4+mi][(nh)*2+ni] = __builtin_amdgcn_mfma_f32_16x16x32_bf16( \
            aF[mi][0], BF[ni][0], acc[(mh)*4+mi][(nh)*2+ni], 0, 0, 0); \
        acc[(mh)*4+mi][(nh)*2+ni] = __builtin_amdgcn_mfma_f32_16x16x32_bf16( \
            aF[mi][1], BF[ni][1], acc[(mh)*4+mi][(nh)*2+ni], 0, 0, 0); } \
    __builtin_amdgcn_s_setprio(0); } while (0)

#define GEMM_PROLOGUE_G(SA, SB) do { \
    SA(0, 0); SA(1, 0); SB(0, 0); SB(1, 0); \
    SB(0, 1); SB(1, 1); \
    VMC4; BARS; } while (0)

#define GEMM_TILE_G(t, NT, SA, SB) do { \
    const char* Ab = smem + (((t) & 1) << 15); \
    const char* Bb = smem + 65536 + (((t) & 1) << 15); \
    /* phase 0 */ \
    READ_A(0); READ_B(0, bF0); \
    if ((t) + 1 < (NT)) SA(0, (t) + 1); \
    BARS; WLG; QUAD(0, 0, bF0); BARS; \
    /* phase 1 */ \
    READ_B(1, bF1); \
    if ((t) + 1 < (NT)) SA(1, (t) + 1); \
    BARS; WLG; QUAD(0, 1, bF1); BARS; \
    /* phase 2 */ \
    READ_A(1); \
    if ((t) + 2 < (NT)) SB(0, (t) + 2); \
    BARS; WLG; QUAD(1, 1, bF1); BARS; \
    /* phase 3 */ \
    if ((t) + 2 < (NT)) SB(1, (t) + 2); \
    BARS; WLG; QUAD(1, 0, bF0); \
    if ((t) + 2 < (NT)) { VMC4; } else { VMC0; } \
    BARS; } while (0)

// ---------------------------------------------------------------------------
// Kernel 6: GEMM1 (all experts): h[e] = gelu(gather(x)[C,D] @ W1t[e]^T + b1[e])
// M=C=2048, N=F=4096, K=D=1024. Grid 256 blocks x 512 thr, 1/CU.
// Each block chains 4 consecutive n-panels (same m0) as ONE 64-K-tile
// pipeline: one prologue drain instead of 4; A gather offsets computed once;
// LDS-free epilogue at segment seams (bias preloaded, no mid-pipeline loads).
// wg>>5 = XCD = expert: whole-XCD L2 holds one expert's weights.
// ---------------------------------------------------------------------------
__global__ __launch_bounds__(512, 2) void gemm1_kernel(
    const __hip_bfloat16* __restrict__ xb,   // [T][D]
    const __hip_bfloat16* __restrict__ W1t,  // [E][F][D]
    const float* __restrict__ b1,            // [E][F]
    const int* __restrict__ topidx,          // [E][C]
    __hip_bfloat16* __restrict__ hbuf)       // [E][C][F]
{
    __shared__ __align__(16) char smem[131072];   // [A0|A1|B0|B1] x 32 KiB
    const int tid = threadIdx.x;
    const int w = tid >> 6, lane = tid & 63;
    const int wr = w >> 2, wc = w & 3;
    const int fr = lane & 15, qlane = lane >> 4;

    const int bid = blockIdx.x;                    // 256 blocks, 256 % 8 == 0
    const int wg  = (bid & 7) * 32 + (bid >> 3);
    const int nc  = wg & 3;                        // chain of n-panels nc*4..+3
    const int m0  = ((wg >> 2) & 7) * 256;
    const int e   = wg >> 5;                       // one expert per XCD
    const int nc0 = nc * 1024;                     // first n of chain

    const char* Abase = (const char*)xb;
    const char* Bbase = (const char*)(W1t + (size_t)e * F_FFN * D_HID);

    // staging source byte offsets (inverse-swizzled column chunk)
    const int cc = (tid & 7) ^ ((tid >> 3) & 7);
    int aog[2][2], bog[2][2];
#pragma unroll
    for (int hh = 0; hh < 2; ++hh)
#pragma unroll
        for (int j = 0; j < 2; ++j) {
            int r   = m0 + hh * 128 + j * 64 + (tid >> 3);
            int tok = topidx[e * C_CAP + r];
            aog[hh][j] = (tok * D_HID + cc * 8) * 2;
            int n = nc0 + hh * 128 + j * 64 + (tid >> 3);
            bog[hh][j] = (n * D_HID + cc * 8) * 2;
        }

    // preload bias for all 4 panels (no loads inside the pipeline/epilogue)
    float b1all[4][4];
#pragma unroll
    for (int p = 0; p < 4; ++p)
#pragma unroll
        for (int ni = 0; ni < 4; ++ni)
            b1all[p][ni] = b1[e * F_FFN + nc0 + p * 256 + wc * 64 + ni * 16 + fr];

    const int arow = (wr * 128 + fr) * 128;
    const int brow = (wc * 64 + fr) * 128;
    const int kc0  = ((qlane)     ^ (lane & 7)) * 16;
    const int kc1  = ((4 + qlane) ^ (lane & 7)) * 16;

    bf16x8 aF[4][2], bF0[2][2], bF1[2][2];
    f32x4 acc[8][4];
#pragma unroll
    for (int mi = 0; mi < 8; ++mi)
#pragma unroll
        for (int ni = 0; ni < 4; ++ni) acc[mi][ni] = (f32x4){0.f, 0.f, 0.f, 0.f};

    GEMM_PROLOGUE_G(STG1_A, STG1_B);
    const int q4 = qlane * 4;
#pragma unroll 1
    for (int p = 0; p < 4; ++p) {
#pragma unroll 2
        for (int tl = 0; tl < 16; ++tl) {
            const int t = p * 16 + tl;
            GEMM_TILE_G(t, 64, STG1_A, STG1_B);
        }
        // Epilogue for panel p: bias + gelu -> bf16, direct stores (no LDS,
        // no barrier; next segment's stages already in flight keep the pipe
        // warm). 16 consecutive lanes store 32 contiguous B per ni.
        const int n0p = nc0 + p * 256;
#pragma unroll
        for (int mi = 0; mi < 8; ++mi) {
#pragma unroll
            for (int r = 0; r < 4; ++r) {
                size_t row = (size_t)e * C_CAP + m0 + wr * 128 + mi * 16 + q4 + r;
                __hip_bfloat16* orow = hbuf + row * F_FFN + n0p + wc * 64;
#pragma unroll
                for (int ni = 0; ni < 4; ++ni)
                    orow[ni * 16 + fr] =
                        __float2bfloat16(gelu_fast(acc[mi][ni][r] + b1all[p][ni]));
            }
#pragma unroll
            for (int ni = 0; ni < 4; ++ni) acc[mi][ni] = (f32x4){0.f, 0.f, 0.f, 0.f};
        }
    }
}

// ---------------------------------------------------------------------------
// Kernel 7: GEMM2 (all experts): yo[e][c] = (h[e] @ W2t[e]^T + b2[e]) * gate
// M=C=2048, N=D=1024, K=F=4096. Grid 256 blocks x 512 thr (1/CU), NT=64.
// ---------------------------------------------------------------------------
__global__ __launch_bounds__(512, 2) void gemm2_kernel(
    const __hip_bfloat16* __restrict__ hbuf, // [E][C][F]
    const __hip_bfloat16* __restrict__ W2t,  // [E][D][F]
    const float* __restrict__ b2,            // [E][D]
    const float* __restrict__ topval,        // [E][C]
    float* __restrict__ yo)                  // [E][C][D]
{
    __shared__ __align__(16) char smem[131072];
    const int tid = threadIdx.x;
    const int w = tid >> 6, lane = tid & 63;
    const int wr = w >> 2, wc = w & 3;
    const int fr = lane & 15, qlane = lane >> 4;

    const int bid = blockIdx.x;
    const int wg  = (bid & 7) * 32 + (bid >> 3);   // 256 % 8 == 0
    const int n0  = (wg & 3) * 256;
    const int m0  = ((wg >> 2) & 7) * 256;
    const int e   = wg >> 5;                        // one expert per XCD

    const char* Abase = (const char*)(hbuf + (size_t)e * C_CAP * F_FFN);
    const char* Bbase = (const char*)(W2t + (size_t)e * D_HID * F_FFN);

    const int cc = (tid & 7) ^ ((tid >> 3) & 7);
    int aog[2][2], bog[2][2];
#pragma unroll
    for (int hh = 0; hh < 2; ++hh)
#pragma unroll
        for (int j = 0; j < 2; ++j) {
            int r = m0 + hh * 128 + j * 64 + (tid >> 3);
            aog[hh][j] = (r * F_FFN + cc * 8) * 2;
            int n = n0 + hh * 128 + j * 64 + (tid >> 3);
            bog[hh][j] = (n * F_FFN + cc * 8) * 2;
        }

    const int arow = (wr * 128 + fr) * 128;
    const int brow = (wc * 64 + fr) * 128;
    const int kc0  = ((qlane)     ^ (lane & 7)) * 16;
    const int kc1  = ((4 + qlane) ^ (lane & 7)) * 16;

    bf16x8 aF[4][2], bF0[2][2], bF1[2][2];
    f32x4 acc[8][4];
#pragma unroll
    for (int mi = 0; mi < 8; ++mi)
#pragma unroll
        for (int ni = 0; ni < 4; ++ni) acc[mi][ni] = (f32x4){0.f, 0.f, 0.f, 0.f};

    GEMM_PROLOGUE_G(STG2_A, STG2_B);
#pragma unroll 2
    for (int t = 0; t < 64; ++t) GEMM_TILE_G(t, 64, STG2_A, STG2_B);

    // Epilogue: bias + gate weight, fp32; 16-lane groups cover 64 B runs.
    const int q4 = qlane * 4;
    float b2v[4];
#pragma unroll
    for (int ni = 0; ni < 4; ++ni)
        b2v[ni] = b2[e * D_HID + n0 + wc * 64 + ni * 16 + fr];
#pragma unroll
    for (int mi = 0; mi < 8; ++mi) {
#pragma unroll
        for (int r = 0; r < 4; ++r) {
            const int row = m0 + wr * 128 + mi * 16 + q4 + r;
            const float g = topval[e * C_CAP + row];
            float* orow = yo + ((size_t)e * C_CAP + row) * D_HID + n0 + wc * 64;
#pragma unroll
            for (int ni = 0; ni < 4; ++ni)
                orow[ni * 16 + fr] = (acc[mi][ni][r] + b2v[ni]) * g;
        }
    }
}

// ---------------------------------------------------------------------------
// Kernel 8: combine — out[t] = sum over inv[t] entries of yo rows.
// ---------------------------------------------------------------------------
__global__ __launch_bounds__(256) void combine_kernel(
    const float* __restrict__ yo, const int* __restrict__ cnt,
    const int* __restrict__ inv, float* __restrict__ out)
{
    const int t = blockIdx.x;
    const int n = cnt[t];
    const int c4 = threadIdx.x * 4;
    float4 a = {0.f, 0.f, 0.f, 0.f};
    for (int k = 0; k < n; ++k) {
        int ec = inv[t * E_EXP + k];
        float4 v = *(const float4*)(yo + (size_t)ec * D_HID + c4);
        a.x += v.x; a.y += v.y; a.z += v.z; a.w += v.w;
    }
    *(float4*)(out + (size_t)t * D_HID + c4) = a;
}

// ---------------------------------------------------------------------------
extern "C" void kernel_launch(void* const* d_in, const int* in_sizes, int n_in,
                              void* d_out, int out_size, void* d_ws, size_t ws_size,
                              hipStream_t stream) {
    const float* x  = (const float*)d_in[0];   // [T, D]
    const float* Wg = (const float*)d_in[1];   // [D, E]
    const float* W1 = (const float*)d_in[2];   // [E, D, F]
    const float* b1 = (const float*)d_in[3];   // [E, F]
    const float* W2 = (const float*)d_in[4];   // [E, F, D]
    const float* b2 = (const float*)d_in[5];   // [E, D]
    float* out = (float*)d_out;                // [T*D] out ++ [1] aux

    // Workspace layout
    char* p = (char*)d_ws;
    float* gatesT = (float*)p;            p += (size_t)E_EXP * T_TOK * 4;      // 256 KB
    int*   topidx = (int*)p;              p += (size_t)E_EXP * C_CAP * 4;      // 64 KB
    float* topval = (float*)p;            p += (size_t)E_EXP * C_CAP * 4;      // 64 KB
    int*   cnt    = (int*)p;              p += (size_t)T_TOK * 4;              // 32 KB
    int*   inv    = (int*)p;              p += (size_t)T_TOK * E_EXP * 4;      // 256 KB
    __hip_bfloat16* x_bf = (__hip_bfloat16*)p;  p += (size_t)T_TOK * D_HID * 2;         // 16.8 MB
    __hip_bfloat16* W1t  = (__hip_bfloat16*)p;  p += (size_t)E_EXP * D_HID * F_FFN * 2; // 67 MB
    __hip_bfloat16* W2t  = (__hip_bfloat16*)p;  p += (size_t)E_EXP * D_HID * F_FFN * 2; // 67 MB
    __hip_bfloat16* hbuf = (__hip_bfloat16*)p;  p += (size_t)E_EXP * C_CAP * F_FFN * 2; // 134 MB
    // yo aliases W1t (dead after gemm1; gemm2 writes yo, combine reads it).
    float* yo = (float*)W1t;   // E*C*D*4 = 67 MB, exactly W1t's size

    hipMemsetAsync(cnt, 0, (size_t)T_TOK * 4, stream);

    // gating fuses x->bf16 convert and writes the (constant) aux loss
    gating_kernel<<<T_TOK / 4, 256, 0, stream>>>(
        x, Wg, gatesT, x_bf, out + (size_t)T_TOK * D_HID);
    topk_kernel<<<E_EXP, 1024, 0, stream>>>(gatesT, topidx, topval, cnt, inv);

    // weight transposes (fp32 -> bf16)
    {
        dim3 g(F_FFN / 64, D_HID / 64, E_EXP);   // W1 [D,F] -> W1t [F,D]
        transpose_bf16_kernel<<<g, 256, 0, stream>>>(W1, W1t, D_HID, F_FFN);
    }
    {
        dim3 g(D_HID / 64, F_FFN / 64, E_EXP);   // W2 [F,D] -> W2t [D,F]
        transpose_bf16_kernel<<<g, 256, 0, stream>>>(W2, W2t, F_FFN, D_HID);
    }

    // Batched expert FFN: 256x256 8-phase MFMA GEMMs
    gemm1_kernel<<<256, 512, 0, stream>>>(x_bf, W1t, b1, topidx, hbuf);
    gemm2_kernel<<<256, 512, 0, stream>>>(hbuf, W2t, b2, topval, yo);
    combine_kernel<<<T_TOK, 256, 0, stream>>>(yo, cnt, inv, out);
}